// Round 1
// baseline (165.737 us; speedup 1.0000x reference)
//
#include <hip/hip_runtime.h>

#define BB 64
#define NN 512
#define FD 64

typedef short bf16x8 __attribute__((ext_vector_type(8)));
typedef float f32x4 __attribute__((ext_vector_type(4)));

__device__ __forceinline__ unsigned short f2bf(float f){
    unsigned u = __builtin_bit_cast(unsigned, f);
    u += 0x7fffu + ((u >> 16) & 1u);           // RNE
    return (unsigned short)(u >> 16);
}
__device__ __forceinline__ float bf2f(unsigned short h){
    unsigned u = ((unsigned)h) << 16;
    return __builtin_bit_cast(float, u);
}
__device__ __forceinline__ float fast_tanh(float x){
    float e = __expf(2.0f * x);                 // inf -> 1, 0 -> -1: saturates correctly
    return 1.0f - 2.0f * __builtin_amdgcn_rcpf(e + 1.0f);
}
__device__ __forceinline__ bf16x8 pack8(float4 a, float4 b){
    bf16x8 r;
    r[0]=(short)f2bf(a.x); r[1]=(short)f2bf(a.y); r[2]=(short)f2bf(a.z); r[3]=(short)f2bf(a.w);
    r[4]=(short)f2bf(b.x); r[5]=(short)f2bf(b.y); r[6]=(short)f2bf(b.z); r[7]=(short)f2bf(b.w);
    return r;
}

// XW = X @ W via MFMA; emits XWh[b][n][f] and XWt[b][f][n] (bf16).
// k_prep folded in: each block transposes W itself (16KB, L2-hot);
// block 0 additionally computes colsum[d] = sum_i a[i][d].
__global__ __launch_bounds__(256) void k_xw(const float* __restrict__ X,
                                            const float* __restrict__ W,
                                            const float* __restrict__ a,
                                            float* __restrict__ colsum,
                                            unsigned short* __restrict__ XWh,
                                            unsigned short* __restrict__ XWt){
    __shared__ float Wf[64][68];
    __shared__ float cpart[4][64];
    __shared__ unsigned short Xl[64][72];
    __shared__ unsigned short Wtl[64][72];
    __shared__ unsigned short Cl[64][72];    // C natural [n][f]
    __shared__ unsigned short ClT[64][72];   // C transposed [f][n]
    int t = threadIdx.x;
    int row0 = blockIdx.x * 64;
    int r = t >> 2, c0 = (t & 3) * 16;
    {
        const float4* srcW = (const float4*)&W[r*64 + c0];
        #pragma unroll
        for (int q = 0; q < 4; q++) *(float4*)&Wf[r][c0 + q*4] = srcW[q];
        const float4* srcX = (const float4*)&X[(row0 + r)*FD + c0];
        #pragma unroll
        for (int q = 0; q < 4; q++){
            float4 v = srcX[q];
            ushort4 h; h.x=f2bf(v.x); h.y=f2bf(v.y); h.z=f2bf(v.z); h.w=f2bf(v.w);
            *(ushort4*)&Xl[r][c0 + q*4] = h;
        }
    }
    if (blockIdx.x == 0){
        int d = t & 63, part = t >> 6;
        float s = 0.f;
        #pragma unroll
        for (int i = 0; i < 16; i++) s += a[(part*16 + i)*64 + d];
        cpart[part][d] = s;
    }
    __syncthreads();
    // Wtl[d][c] = bf16(W[c][d])
    #pragma unroll
    for (int q = 0; q < 4; q++){
        ushort4 o;
        #pragma unroll
        for (int jj = 0; jj < 4; jj++)
            ((unsigned short*)&o)[jj] = f2bf(Wf[c0 + q*4 + jj][r]);
        *(ushort4*)&Wtl[r][c0 + q*4] = o;
    }
    if (blockIdx.x == 0 && t < 64)
        colsum[t] = cpart[0][t] + cpart[1][t] + cpart[2][t] + cpart[3][t];
    __syncthreads();
    int lane = t & 63, w = t >> 6, l15 = lane & 15, quad = lane >> 4;
    f32x4 acc[4] = {{0,0,0,0},{0,0,0,0},{0,0,0,0},{0,0,0,0}};
    #pragma unroll
    for (int ks = 0; ks < 2; ks++){
        bf16x8 af = *(const bf16x8*)&Xl[w*16 + l15][ks*32 + quad*8];
        #pragma unroll
        for (int nt = 0; nt < 4; nt++){
            bf16x8 bfr = *(const bf16x8*)&Wtl[nt*16 + l15][ks*32 + quad*8];
            acc[nt] = __builtin_amdgcn_mfma_f32_16x16x32_bf16(af, bfr, acc[nt], 0, 0, 0);
        }
    }
    #pragma unroll
    for (int nt = 0; nt < 4; nt++)
        #pragma unroll
        for (int rg = 0; rg < 4; rg++){
            unsigned short hb = f2bf(acc[nt][rg]);
            Cl [w*16 + quad*4 + rg][nt*16 + l15] = hb;
            ClT[nt*16 + l15][w*16 + quad*4 + rg] = hb;
        }
    __syncthreads();
    int b = blockIdx.x >> 3, n0 = (blockIdx.x & 7) * 64;
    {
        uint4 v0 = *(const uint4*)&Cl[r][c0];
        uint4 v1 = *(const uint4*)&Cl[r][c0 + 8];
        *(uint4*)&XWh[(row0 + r)*FD + c0]     = v0;
        *(uint4*)&XWh[(row0 + r)*FD + c0 + 8] = v1;
    }
    {
        uint4 v0 = *(const uint4*)&ClT[r][c0];
        uint4 v1 = *(const uint4*)&ClT[r][c0 + 8];
        *(uint4*)&XWt[(b*64 + r)*NN + n0 + c0]     = v0;
        *(uint4*)&XWt[(b*64 + r)*NN + n0 + c0 + 8] = v1;
    }
}

// Fused: M = (A_ @ XW) * diag(colsum); H = tanh(M @ XW^T + rowsum*bias_a) @ XW + bias_W.
// Restructured: A-fragments built direct from global (f32->bf16 in-register, rowsum from
// the same registers via shfl); all B-fragments read 16B/lane straight from L2-resident
// XWh/XWt. Only the M/P tile round-trips LDS (double-buffered): 9 barriers total vs 40.
// Grid is (b, it) so all 8 i-tiles of a batch land on one XCD (linear%8 == b%8).
__global__ __launch_bounds__(512) void k_fused(const float* __restrict__ A,
                                               const unsigned short* __restrict__ XWh,
                                               const unsigned short* __restrict__ XWt,
                                               const float* __restrict__ colsum,
                                               const int* __restrict__ Ni,
                                               const float* __restrict__ bias_a,
                                               const float* __restrict__ bias_W,
                                               float* __restrict__ H){
    __shared__ unsigned short mp[2][64][72];   // buf0: M tile, then P tiles ping-pong
    __shared__ float rsl[64];
    int t = threadIdx.x;
    int b = blockIdx.x, it = blockIdx.y;
    int i0 = it * 64;
    int Nb = (Ni[1] == 0) ? Ni[2*b] : Ni[b];   // int64 vs int32 layout
    int lane = t & 63, w = t >> 6, l15 = lane & 15, quad = lane >> 4;
    int wr = w & 3, wc = w >> 2;
    const float* Arow = A + (size_t)(b*NN + i0 + wr*16 + l15)*NN + quad*8;
    const unsigned short* XWtb = XWt + b*64*NN;
    const unsigned short* XWhb = XWh + b*NN*FD;

    // ---- phase A: M = A_ @ XW, barrier-free streamed loop ----
    f32x4 acc[2] = {{0,0,0,0},{0,0,0,0}};
    float rs = 0.f;
    #pragma unroll
    for (int c = 0; c < 8; c++){
        bf16x8 af[2];
        #pragma unroll
        for (int ks = 0; ks < 2; ks++){
            float4 v0 = *(const float4*)&Arow[c*64 + ks*32];
            float4 v1 = *(const float4*)&Arow[c*64 + ks*32 + 4];
            rs += (v0.x + v0.y) + (v0.z + v0.w) + (v1.x + v1.y) + (v1.z + v1.w);
            af[ks] = pack8(v0, v1);
        }
        #pragma unroll
        for (int ks = 0; ks < 2; ks++)
            #pragma unroll
            for (int nt = 0; nt < 2; nt++){
                bf16x8 bfr = *(const bf16x8*)&XWtb[(wc*32 + nt*16 + l15)*NN + c*64 + ks*32 + quad*8];
                acc[nt] = __builtin_amdgcn_mfma_f32_16x16x32_bf16(af[ks], bfr, acc[nt], 0, 0, 0);
            }
    }
    // diagonal of A_ (identity on first Nb rows): acc += XW[i][f]
    #pragma unroll
    for (int nt = 0; nt < 2; nt++)
        #pragma unroll
        for (int rg = 0; rg < 4; rg++){
            int i = i0 + wr*16 + quad*4 + rg;
            if (i < Nb) acc[nt][rg] += bf2f(XWhb[i*FD + wc*32 + nt*16 + l15]);
        }
    // rowsum of A row: reduce per-lane partials over quads (wc==0 waves only)
    if (wc == 0){
        float r1 = rs + __shfl_xor(rs, 16);
        float r2 = r1 + __shfl_xor(r1, 32);
        if (lane < 16) rsl[wr*16 + lane] = r2;
    }
    // M = acc * colsum[col] -> mp[0] (row-major, A-operand readable)
    #pragma unroll
    for (int nt = 0; nt < 2; nt++){
        float cs = colsum[wc*32 + nt*16 + l15];
        #pragma unroll
        for (int rg = 0; rg < 4; rg++)
            mp[0][wr*16 + quad*4 + rg][wc*32 + nt*16 + l15] = f2bf(acc[nt][rg] * cs);
    }
    __syncthreads();                                   // barrier #1 (M + rsl ready)
    bf16x8 maf[2];
    maf[0] = *(const bf16x8*)&mp[0][wr*16 + l15][quad*8];
    maf[1] = *(const bf16x8*)&mp[0][wr*16 + l15][32 + quad*8];
    float rs_r[4];
    #pragma unroll
    for (int rg = 0; rg < 4; rg++){
        int i = i0 + wr*16 + quad*4 + rg;
        rs_r[rg] = rsl[wr*16 + quad*4 + rg] + ((i < Nb) ? 1.f : 0.f);
    }

    // ---- phase B: 8 j-chunks, P double-buffered, 1 barrier per chunk ----
    f32x4 hacc[2] = {{0,0,0,0},{0,0,0,0}};
    #pragma unroll
    for (int jt = 0; jt < 8; jt++){
        int pb = (jt + 1) & 1;                 // jt0->buf1 (keeps M alive for maf reads)
        #pragma unroll
        for (int nt = 0; nt < 2; nt++){
            float bv = bias_a[jt*64 + wc*32 + nt*16 + l15];
            f32x4 arg = { rs_r[0]*bv, rs_r[1]*bv, rs_r[2]*bv, rs_r[3]*bv };
            #pragma unroll
            for (int ks = 0; ks < 2; ks++){
                bf16x8 bfr = *(const bf16x8*)&XWhb[(jt*64 + wc*32 + nt*16 + l15)*FD + ks*32 + quad*8];
                arg = __builtin_amdgcn_mfma_f32_16x16x32_bf16(maf[ks], bfr, arg, 0, 0, 0);
            }
            #pragma unroll
            for (int rg = 0; rg < 4; rg++)
                mp[pb][wr*16 + quad*4 + rg][wc*32 + nt*16 + l15] = f2bf(fast_tanh(arg[rg]));
        }
        __syncthreads();                       // P(jt) ready; prior buffer's readers done
        #pragma unroll
        for (int ks = 0; ks < 2; ks++){
            bf16x8 paf = *(const bf16x8*)&mp[pb][wr*16 + l15][ks*32 + quad*8];
            #pragma unroll
            for (int dt = 0; dt < 2; dt++){
                bf16x8 bfr = *(const bf16x8*)&XWtb[(wc*32 + dt*16 + l15)*NN + jt*64 + ks*32 + quad*8];
                hacc[dt] = __builtin_amdgcn_mfma_f32_16x16x32_bf16(paf, bfr, hacc[dt], 0, 0, 0);
            }
        }
    }
    #pragma unroll
    for (int dt = 0; dt < 2; dt++){
        float bw = bias_W[wc*32 + dt*16 + l15];
        #pragma unroll
        for (int rg = 0; rg < 4; rg++)
            H[(size_t)(b*NN + i0 + wr*16 + quad*4 + rg)*FD + wc*32 + dt*16 + l15] = hacc[dt][rg] + bw;
    }
}

extern "C" void kernel_launch(void* const* d_in, const int* in_sizes, int n_in,
                              void* d_out, int out_size, void* d_ws, size_t ws_size,
                              hipStream_t stream){
    const float* X      = (const float*)d_in[0];
    const float* A      = (const float*)d_in[1];
    const int*   N      = (const int*)  d_in[2];
    const float* W      = (const float*)d_in[3];
    const float* a      = (const float*)d_in[4];
    const float* bias_W = (const float*)d_in[5];
    const float* bias_a = (const float*)d_in[6];
    float* H = (float*)d_out;
    char* ws = (char*)d_ws;

    unsigned short* XWh    = (unsigned short*)(ws);                    // 4 MB
    unsigned short* XWt    = (unsigned short*)(ws + (4u<<20));         // 4 MB
    float*          colsum = (float*)(ws + (8u<<20));                  // 256 B

    k_xw   <<<BB * NN / 64, 256, 0, stream>>>(X, W, a, colsum, XWh, XWt);
    k_fused<<<dim3(BB, 8), 512, 0, stream>>>(A, XWh, XWt, colsum, N, bias_a, bias_W, H);
}

// Round 2
// 136.172 us; speedup vs baseline: 1.2171x; 1.2171x over previous
//
#include <hip/hip_runtime.h>

#define BB 64
#define NN 512
#define FD 64

typedef short bf16x8 __attribute__((ext_vector_type(8)));
typedef float f32x4 __attribute__((ext_vector_type(4)));

__device__ __forceinline__ unsigned short f2bf(float f){
    unsigned u = __builtin_bit_cast(unsigned, f);
    u += 0x7fffu + ((u >> 16) & 1u);           // RNE
    return (unsigned short)(u >> 16);
}
__device__ __forceinline__ float bf2f(unsigned short h){
    unsigned u = ((unsigned)h) << 16;
    return __builtin_bit_cast(float, u);
}
__device__ __forceinline__ float fast_tanh(float x){
    float e = __expf(2.0f * x);                 // inf -> 1, 0 -> -1: saturates correctly
    return 1.0f - 2.0f * __builtin_amdgcn_rcpf(e + 1.0f);
}
__device__ __forceinline__ bf16x8 pack8(float4 a, float4 b){
    bf16x8 r;
    r[0]=(short)f2bf(a.x); r[1]=(short)f2bf(a.y); r[2]=(short)f2bf(a.z); r[3]=(short)f2bf(a.w);
    r[4]=(short)f2bf(b.x); r[5]=(short)f2bf(b.y); r[6]=(short)f2bf(b.z); r[7]=(short)f2bf(b.w);
    return r;
}

// XW = X @ W via MFMA; emits XWh[b][n][f] and XWt[b][f][n] (bf16).
// k_prep folded in: each block transposes W itself (16KB, L2-hot);
// block 0 additionally computes colsum[d] = sum_i a[i][d].
__global__ __launch_bounds__(256) void k_xw(const float* __restrict__ X,
                                            const float* __restrict__ W,
                                            const float* __restrict__ a,
                                            float* __restrict__ colsum,
                                            unsigned short* __restrict__ XWh,
                                            unsigned short* __restrict__ XWt){
    __shared__ float Wf[64][68];
    __shared__ float cpart[4][64];
    __shared__ unsigned short Xl[64][72];
    __shared__ unsigned short Wtl[64][72];
    __shared__ unsigned short Cl[64][72];    // C natural [n][f]
    __shared__ unsigned short ClT[64][72];   // C transposed [f][n]
    int t = threadIdx.x;
    int row0 = blockIdx.x * 64;
    int r = t >> 2, c0 = (t & 3) * 16;
    {
        const float4* srcW = (const float4*)&W[r*64 + c0];
        #pragma unroll
        for (int q = 0; q < 4; q++) *(float4*)&Wf[r][c0 + q*4] = srcW[q];
        const float4* srcX = (const float4*)&X[(row0 + r)*FD + c0];
        #pragma unroll
        for (int q = 0; q < 4; q++){
            float4 v = srcX[q];
            ushort4 h; h.x=f2bf(v.x); h.y=f2bf(v.y); h.z=f2bf(v.z); h.w=f2bf(v.w);
            *(ushort4*)&Xl[r][c0 + q*4] = h;
        }
    }
    if (blockIdx.x == 0){
        int d = t & 63, part = t >> 6;
        float s = 0.f;
        #pragma unroll
        for (int i = 0; i < 16; i++) s += a[(part*16 + i)*64 + d];
        cpart[part][d] = s;
    }
    __syncthreads();
    // Wtl[d][c] = bf16(W[c][d])
    #pragma unroll
    for (int q = 0; q < 4; q++){
        ushort4 o;
        #pragma unroll
        for (int jj = 0; jj < 4; jj++)
            ((unsigned short*)&o)[jj] = f2bf(Wf[c0 + q*4 + jj][r]);
        *(ushort4*)&Wtl[r][c0 + q*4] = o;
    }
    if (blockIdx.x == 0 && t < 64)
        colsum[t] = cpart[0][t] + cpart[1][t] + cpart[2][t] + cpart[3][t];
    __syncthreads();
    int lane = t & 63, w = t >> 6, l15 = lane & 15, quad = lane >> 4;
    f32x4 acc[4] = {{0,0,0,0},{0,0,0,0},{0,0,0,0},{0,0,0,0}};
    #pragma unroll
    for (int ks = 0; ks < 2; ks++){
        bf16x8 af = *(const bf16x8*)&Xl[w*16 + l15][ks*32 + quad*8];
        #pragma unroll
        for (int nt = 0; nt < 4; nt++){
            bf16x8 bfr = *(const bf16x8*)&Wtl[nt*16 + l15][ks*32 + quad*8];
            acc[nt] = __builtin_amdgcn_mfma_f32_16x16x32_bf16(af, bfr, acc[nt], 0, 0, 0);
        }
    }
    #pragma unroll
    for (int nt = 0; nt < 4; nt++)
        #pragma unroll
        for (int rg = 0; rg < 4; rg++){
            unsigned short hb = f2bf(acc[nt][rg]);
            Cl [w*16 + quad*4 + rg][nt*16 + l15] = hb;
            ClT[nt*16 + l15][w*16 + quad*4 + rg] = hb;
        }
    __syncthreads();
    int b = blockIdx.x >> 3, n0 = (blockIdx.x & 7) * 64;
    {
        uint4 v0 = *(const uint4*)&Cl[r][c0];
        uint4 v1 = *(const uint4*)&Cl[r][c0 + 8];
        *(uint4*)&XWh[(row0 + r)*FD + c0]     = v0;
        *(uint4*)&XWh[(row0 + r)*FD + c0 + 8] = v1;
    }
    {
        uint4 v0 = *(const uint4*)&ClT[r][c0];
        uint4 v1 = *(const uint4*)&ClT[r][c0 + 8];
        *(uint4*)&XWt[(b*64 + r)*NN + n0 + c0]     = v0;
        *(uint4*)&XWt[(b*64 + r)*NN + n0 + c0 + 8] = v1;
    }
}

// Fused: M = (A_ @ XW) * diag(colsum); H = tanh(M @ XW^T + rowsum*bias_a) @ XW + bias_W.
// v2: per-batch XWt (64KB) and XWh (64KB) staged ONCE into LDS in a prologue (padded so
// every b128 fragment read is <=2-way bank-aliased = free). Phase A then streams A with
// in-register bf16 fragment packing (no LDS, no barriers, deep ILP); phase B is fully
// LDS-resident with a double-buffered P tile -> 1 barrier per j-chunk. ~10 barriers total
// vs 40 in the staged version and no per-MFMA global gathers (the round-1 mistake).
// Grid (b, it): all 8 i-tiles of batch b land on XCD b%8 -> prologue reads are L2-hot.
__global__ __launch_bounds__(512, 2) void k_fused(const float* __restrict__ A,
                                               const unsigned short* __restrict__ XWh,
                                               const unsigned short* __restrict__ XWt,
                                               const float* __restrict__ colsum,
                                               const int* __restrict__ Ni,
                                               const float* __restrict__ bias_a,
                                               const float* __restrict__ bias_W,
                                               float* __restrict__ H){
    __shared__ unsigned short XWtL[64][516];   // [f][n], pad 4 -> row stride 1032B (bank+2/row)
    __shared__ unsigned short XWhL[512][68];   // [n][f], pad 4 -> row stride 136B  (bank+2/row)
    __shared__ unsigned short P[2][64][72];    // M tile (buf0), then P tiles ping-pong
    __shared__ float bl[512];                  // bias_a
    __shared__ float csl[64];
    __shared__ float rsl[64];
    int t = threadIdx.x;
    int b = blockIdx.x, it = blockIdx.y;
    int i0 = it * 64;
    int Nb = (Ni[1] == 0) ? Ni[2*b] : Ni[b];   // int64 vs int32 layout
    int lane = t & 63, w = t >> 6, l15 = lane & 15, quad = lane >> 4;
    int wr = w & 3, wc = w >> 2;
    const unsigned short* XWtb = XWt + b*64*NN;
    const unsigned short* XWhb = XWh + b*NN*FD;
    const float* Arow = A + (size_t)(b*NN + i0 + wr*16 + l15)*NN + quad*8;

    // ---- prologue: stage full XWt[b] and XWh[b] into LDS (coalesced 16B chunks) ----
    #pragma unroll
    for (int q = 0; q < 8; q++){
        int m = t + 512*q;                     // 4096 x 16B chunks of XWt[b]
        *(uint4*)&XWtL[m >> 6][(m & 63)*8] = *(const uint4*)&XWtb[(m >> 6)*NN + (m & 63)*8];
    }
    #pragma unroll
    for (int q = 0; q < 8; q++){
        int m = t + 512*q;                     // 4096 x 16B chunks of XWh[b]
        *(uint4*)&XWhL[m >> 3][(m & 7)*8] = *(const uint4*)&XWhb[(m >> 3)*FD + (m & 7)*8];
    }
    bl[t] = bias_a[t];
    if (t < 64) csl[t] = colsum[t];
    __syncthreads();                           // barrier #1: staging visible

    // ---- phase A: M = A_ @ XW, barrier-free; A fragments packed in-register ----
    f32x4 acc[2] = {{0,0,0,0},{0,0,0,0}};
    float rs = 0.f;
    #pragma unroll
    for (int c = 0; c < 8; c++){
        bf16x8 af[2];
        #pragma unroll
        for (int ks = 0; ks < 2; ks++){
            float4 v0 = *(const float4*)&Arow[c*64 + ks*32];
            float4 v1 = *(const float4*)&Arow[c*64 + ks*32 + 4];
            rs += (v0.x + v0.y) + (v0.z + v0.w) + (v1.x + v1.y) + (v1.z + v1.w);
            af[ks] = pack8(v0, v1);
        }
        #pragma unroll
        for (int ks = 0; ks < 2; ks++)
            #pragma unroll
            for (int nt = 0; nt < 2; nt++){
                bf16x8 bfr = *(const bf16x8*)&XWtL[wc*32 + nt*16 + l15][c*64 + ks*32 + quad*8];
                acc[nt] = __builtin_amdgcn_mfma_f32_16x16x32_bf16(af[ks], bfr, acc[nt], 0, 0, 0);
            }
    }
    // diagonal of A_ (identity on first Nb rows): acc += XW[i][f]
    #pragma unroll
    for (int nt = 0; nt < 2; nt++)
        #pragma unroll
        for (int rg = 0; rg < 4; rg++){
            int i = i0 + wr*16 + quad*4 + rg;
            if (i < Nb) acc[nt][rg] += bf2f(XWhL[i][wc*32 + nt*16 + l15]);
        }
    // rowsum of A rows: reduce per-lane partials over quads (wc==0 waves only)
    if (wc == 0){
        float r1 = rs + __shfl_xor(rs, 16);
        float r2 = r1 + __shfl_xor(r1, 32);
        if (lane < 16) rsl[wr*16 + lane] = r2;
    }
    // M = acc * colsum[col] -> P[0] (row-major, A-operand readable)
    #pragma unroll
    for (int nt = 0; nt < 2; nt++){
        float cs = csl[wc*32 + nt*16 + l15];
        #pragma unroll
        for (int rg = 0; rg < 4; rg++)
            P[0][wr*16 + quad*4 + rg][wc*32 + nt*16 + l15] = f2bf(acc[nt][rg] * cs);
    }
    __syncthreads();                           // barrier #2: M + rsl ready
    bf16x8 maf[2];
    maf[0] = *(const bf16x8*)&P[0][wr*16 + l15][quad*8];
    maf[1] = *(const bf16x8*)&P[0][wr*16 + l15][32 + quad*8];
    float rs_r[4];
    #pragma unroll
    for (int rg = 0; rg < 4; rg++){
        int i = i0 + wr*16 + quad*4 + rg;
        rs_r[rg] = rsl[wr*16 + quad*4 + rg] + ((i < Nb) ? 1.f : 0.f);
    }

    // ---- phase B: 8 j-chunks, fully LDS-resident, P double-buffered, 1 barrier/chunk ----
    f32x4 hacc[2] = {{0,0,0,0},{0,0,0,0}};
    #pragma unroll
    for (int jt = 0; jt < 8; jt++){
        int pb = (jt + 1) & 1;                 // jt0 -> buf1 (maf regs already loaded)
        #pragma unroll
        for (int nt = 0; nt < 2; nt++){
            float bv = bl[jt*64 + wc*32 + nt*16 + l15];
            f32x4 arg = { rs_r[0]*bv, rs_r[1]*bv, rs_r[2]*bv, rs_r[3]*bv };
            #pragma unroll
            for (int ks = 0; ks < 2; ks++){
                bf16x8 bfr = *(const bf16x8*)&XWhL[jt*64 + wc*32 + nt*16 + l15][ks*32 + quad*8];
                arg = __builtin_amdgcn_mfma_f32_16x16x32_bf16(maf[ks], bfr, arg, 0, 0, 0);
            }
            #pragma unroll
            for (int rg = 0; rg < 4; rg++)
                P[pb][wr*16 + quad*4 + rg][wc*32 + nt*16 + l15] = f2bf(fast_tanh(arg[rg]));
        }
        __syncthreads();                       // P(jt) visible; prior-buffer readers done
        #pragma unroll
        for (int ks = 0; ks < 2; ks++){
            bf16x8 paf = *(const bf16x8*)&P[pb][wr*16 + l15][ks*32 + quad*8];
            #pragma unroll
            for (int dt = 0; dt < 2; dt++){
                bf16x8 bfr = *(const bf16x8*)&XWtL[wc*32 + dt*16 + l15][jt*64 + ks*32 + quad*8];
                hacc[dt] = __builtin_amdgcn_mfma_f32_16x16x32_bf16(paf, bfr, hacc[dt], 0, 0, 0);
            }
        }
    }
    #pragma unroll
    for (int dt = 0; dt < 2; dt++){
        float bw = bias_W[wc*32 + dt*16 + l15];
        #pragma unroll
        for (int rg = 0; rg < 4; rg++)
            H[(size_t)(b*NN + i0 + wr*16 + quad*4 + rg)*FD + wc*32 + dt*16 + l15] = hacc[dt][rg] + bw;
    }
}

extern "C" void kernel_launch(void* const* d_in, const int* in_sizes, int n_in,
                              void* d_out, int out_size, void* d_ws, size_t ws_size,
                              hipStream_t stream){
    const float* X      = (const float*)d_in[0];
    const float* A      = (const float*)d_in[1];
    const int*   N      = (const int*)  d_in[2];
    const float* W      = (const float*)d_in[3];
    const float* a      = (const float*)d_in[4];
    const float* bias_W = (const float*)d_in[5];
    const float* bias_a = (const float*)d_in[6];
    float* H = (float*)d_out;
    char* ws = (char*)d_ws;

    unsigned short* XWh    = (unsigned short*)(ws);                    // 4 MB
    unsigned short* XWt    = (unsigned short*)(ws + (4u<<20));         // 4 MB
    float*          colsum = (float*)(ws + (8u<<20));                  // 256 B

    k_xw   <<<BB * NN / 64, 256, 0, stream>>>(X, W, a, colsum, XWh, XWt);
    k_fused<<<dim3(BB, 8), 512, 0, stream>>>(A, XWh, XWt, colsum, N, bias_a, bias_W, H);
}

// Round 3
// 127.994 us; speedup vs baseline: 1.2949x; 1.0639x over previous
//
#include <hip/hip_runtime.h>

#define BB 64
#define NN 512
#define FD 64

typedef short bf16x8 __attribute__((ext_vector_type(8)));
typedef float f32x4 __attribute__((ext_vector_type(4)));

__device__ __forceinline__ unsigned short f2bf(float f){
    unsigned u = __builtin_bit_cast(unsigned, f);
    u += 0x7fffu + ((u >> 16) & 1u);           // RNE
    return (unsigned short)(u >> 16);
}
__device__ __forceinline__ float bf2f(unsigned short h){
    unsigned u = ((unsigned)h) << 16;
    return __builtin_bit_cast(float, u);
}
__device__ __forceinline__ float fast_tanh(float x){
    float e = __expf(2.0f * x);                 // inf -> 1, 0 -> -1: saturates correctly
    return 1.0f - 2.0f * __builtin_amdgcn_rcpf(e + 1.0f);
}
__device__ __forceinline__ bf16x8 pack8(float4 a, float4 b){
    bf16x8 r;
    r[0]=(short)f2bf(a.x); r[1]=(short)f2bf(a.y); r[2]=(short)f2bf(a.z); r[3]=(short)f2bf(a.w);
    r[4]=(short)f2bf(b.x); r[5]=(short)f2bf(b.y); r[6]=(short)f2bf(b.z); r[7]=(short)f2bf(b.w);
    return r;
}

// XW = X @ W via MFMA; emits XWh[b][n][f] and XWt[b][f][n] (bf16).
// k_prep folded in: each block transposes W itself (16KB, L2-hot);
// block 0 additionally computes colsum[d] = sum_i a[i][d].
__global__ __launch_bounds__(256) void k_xw(const float* __restrict__ X,
                                            const float* __restrict__ W,
                                            const float* __restrict__ a,
                                            float* __restrict__ colsum,
                                            unsigned short* __restrict__ XWh,
                                            unsigned short* __restrict__ XWt){
    __shared__ float Wf[64][68];
    __shared__ float cpart[4][64];
    __shared__ unsigned short Xl[64][72];
    __shared__ unsigned short Wtl[64][72];
    __shared__ unsigned short Cl[64][72];    // C natural [n][f]
    __shared__ unsigned short ClT[64][72];   // C transposed [f][n]
    int t = threadIdx.x;
    int row0 = blockIdx.x * 64;
    int r = t >> 2, c0 = (t & 3) * 16;
    {
        const float4* srcW = (const float4*)&W[r*64 + c0];
        #pragma unroll
        for (int q = 0; q < 4; q++) *(float4*)&Wf[r][c0 + q*4] = srcW[q];
        const float4* srcX = (const float4*)&X[(row0 + r)*FD + c0];
        #pragma unroll
        for (int q = 0; q < 4; q++){
            float4 v = srcX[q];
            ushort4 h; h.x=f2bf(v.x); h.y=f2bf(v.y); h.z=f2bf(v.z); h.w=f2bf(v.w);
            *(ushort4*)&Xl[r][c0 + q*4] = h;
        }
    }
    if (blockIdx.x == 0){
        int d = t & 63, part = t >> 6;
        float s = 0.f;
        #pragma unroll
        for (int i = 0; i < 16; i++) s += a[(part*16 + i)*64 + d];
        cpart[part][d] = s;
    }
    __syncthreads();
    // Wtl[d][c] = bf16(W[c][d])
    #pragma unroll
    for (int q = 0; q < 4; q++){
        ushort4 o;
        #pragma unroll
        for (int jj = 0; jj < 4; jj++)
            ((unsigned short*)&o)[jj] = f2bf(Wf[c0 + q*4 + jj][r]);
        *(ushort4*)&Wtl[r][c0 + q*4] = o;
    }
    if (blockIdx.x == 0 && t < 64)
        colsum[t] = cpart[0][t] + cpart[1][t] + cpart[2][t] + cpart[3][t];
    __syncthreads();
    int lane = t & 63, w = t >> 6, l15 = lane & 15, quad = lane >> 4;
    f32x4 acc[4] = {{0,0,0,0},{0,0,0,0},{0,0,0,0},{0,0,0,0}};
    #pragma unroll
    for (int ks = 0; ks < 2; ks++){
        bf16x8 af = *(const bf16x8*)&Xl[w*16 + l15][ks*32 + quad*8];
        #pragma unroll
        for (int nt = 0; nt < 4; nt++){
            bf16x8 bfr = *(const bf16x8*)&Wtl[nt*16 + l15][ks*32 + quad*8];
            acc[nt] = __builtin_amdgcn_mfma_f32_16x16x32_bf16(af, bfr, acc[nt], 0, 0, 0);
        }
    }
    #pragma unroll
    for (int nt = 0; nt < 4; nt++)
        #pragma unroll
        for (int rg = 0; rg < 4; rg++){
            unsigned short hb = f2bf(acc[nt][rg]);
            Cl [w*16 + quad*4 + rg][nt*16 + l15] = hb;
            ClT[nt*16 + l15][w*16 + quad*4 + rg] = hb;
        }
    __syncthreads();
    int b = blockIdx.x >> 3, n0 = (blockIdx.x & 7) * 64;
    {
        uint4 v0 = *(const uint4*)&Cl[r][c0];
        uint4 v1 = *(const uint4*)&Cl[r][c0 + 8];
        *(uint4*)&XWh[(row0 + r)*FD + c0]     = v0;
        *(uint4*)&XWh[(row0 + r)*FD + c0 + 8] = v1;
    }
    {
        uint4 v0 = *(const uint4*)&ClT[r][c0];
        uint4 v1 = *(const uint4*)&ClT[r][c0 + 8];
        *(uint4*)&XWt[(b*64 + r)*NN + n0 + c0]     = v0;
        *(uint4*)&XWt[(b*64 + r)*NN + n0 + c0 + 8] = v1;
    }
}

// v3: wave-private strips -> ONE barrier in the whole kernel.
// Block = (batch b, it2); handles i-tiles {it2, it2+4}. Wave w = (tile tl=w>>2,
// row-strip st=w&3): computes its 16-row strip end-to-end: phase A (M strip, all 64 f),
// in-wave rowsum via shfl, C->A transpose of M/P through a PRIVATE LDS strip (lgkmcnt
// only, no __syncthreads), phase B (GEMM1 -> tanh -> GEMM2) with zero inter-wave deps.
// XWt[b]/XWh[b] staged once per block (grid = 256 = 1 block/CU). A streamed with a
// depth-4 register prefetch issued before staging. All LDS row strides 16B-aligned.
__global__ __launch_bounds__(512, 1) void k_fused(const float* __restrict__ A,
                                               const unsigned short* __restrict__ XWh,
                                               const unsigned short* __restrict__ XWt,
                                               const float* __restrict__ colsum,
                                               const int* __restrict__ Ni,
                                               const float* __restrict__ bias_a,
                                               const float* __restrict__ bias_W,
                                               float* __restrict__ H){
    __shared__ unsigned short XWtL[64][520];   // [f][n]  row 1040B, 16B-aligned
    __shared__ unsigned short XWhL[512][72];   // [n][f]  row 144B, 16B-aligned
    __shared__ unsigned short Pl[8][16][72];   // per-wave M/P strip
    __shared__ float bl[512];                  // bias_a
    __shared__ float csl[64];                  // colsum
    int t = threadIdx.x;
    int b = blockIdx.x, it2 = blockIdx.y;
    int lane = t & 63, w = t >> 6, l15 = lane & 15, quad = lane >> 4;
    int tl = w >> 2, st = w & 3;
    int i0 = (it2 + 4*tl) * 64;
    int Nb = (Ni[1] == 0) ? Ni[2*b] : Ni[b];   // int64 vs int32 layout
    const unsigned short* XWtb = XWt + b*64*NN;
    const unsigned short* XWhb = XWh + b*NN*FD;
    const float* Arow = A + (size_t)(b*NN + i0 + st*16 + l15)*NN + quad*8;

    // A prefetch (first 4 k-steps) issued BEFORE staging: HBM latency hides under it
    float4 pa[4][2];
    #pragma unroll
    for (int s = 0; s < 4; s++){
        pa[s][0] = *(const float4*)&Arow[s*32];
        pa[s][1] = *(const float4*)&Arow[s*32 + 4];
    }
    // stage XWt[b] (64x512) + XWh[b] (512x64) into LDS, coalesced 16B chunks
    #pragma unroll
    for (int q = 0; q < 8; q++){
        int m = t + 512*q;
        *(uint4*)&XWtL[m >> 6][(m & 63)*8] = *(const uint4*)&XWtb[(m >> 6)*NN + (m & 63)*8];
    }
    #pragma unroll
    for (int q = 0; q < 8; q++){
        int m = t + 512*q;
        *(uint4*)&XWhL[m >> 3][(m & 7)*8] = *(const uint4*)&XWhb[(m >> 3)*FD + (m & 7)*8];
    }
    bl[t] = bias_a[t];
    if (t < 64) csl[t] = colsum[t];
    __syncthreads();                           // the kernel's ONLY barrier

    // ---- phase A: M strip = (A_ @ XW) rows [st*16,st*16+16), all 64 f ----
    f32x4 acc[4] = {{0,0,0,0},{0,0,0,0},{0,0,0,0},{0,0,0,0}};
    float rs = 0.f;
    #pragma unroll
    for (int s = 0; s < 16; s++){
        float4 v0 = pa[s & 3][0], v1 = pa[s & 3][1];
        if (s < 12){                           // rotate prefetch 4 k-steps ahead
            pa[s & 3][0] = *(const float4*)&Arow[(s + 4)*32];
            pa[s & 3][1] = *(const float4*)&Arow[(s + 4)*32 + 4];
        }
        rs += (v0.x + v0.y) + (v0.z + v0.w) + (v1.x + v1.y) + (v1.z + v1.w);
        bf16x8 af = pack8(v0, v1);
        #pragma unroll
        for (int nt = 0; nt < 4; nt++){
            bf16x8 bfr = *(const bf16x8*)&XWtL[nt*16 + l15][s*32 + quad*8];
            acc[nt] = __builtin_amdgcn_mfma_f32_16x16x32_bf16(af, bfr, acc[nt], 0, 0, 0);
        }
    }
    // diagonal of A_ (identity on first Nb rows): acc += XW[i][f]
    #pragma unroll
    for (int nt = 0; nt < 4; nt++)
        #pragma unroll
        for (int rg = 0; rg < 4; rg++){
            int i = i0 + st*16 + quad*4 + rg;
            if (i < Nb) acc[nt][rg] += bf2f(XWhL[i][nt*16 + l15]);
        }
    // in-wave rowsum: reduce quad partials; every lane then holds rowsum(row l15)
    float rsum = rs;
    rsum += __shfl_xor(rsum, 16);
    rsum += __shfl_xor(rsum, 32);
    // M = acc * colsum[col] -> private strip (C-layout)
    #pragma unroll
    for (int nt = 0; nt < 4; nt++){
        float cs = csl[nt*16 + l15];
        #pragma unroll
        for (int rg = 0; rg < 4; rg++)
            Pl[w][quad*4 + rg][nt*16 + l15] = f2bf(acc[nt][rg] * cs);
    }
    asm volatile("s_waitcnt lgkmcnt(0)" ::: "memory");
    __builtin_amdgcn_sched_barrier(0);
    bf16x8 maf[2];                             // A-layout M fragments (in-wave transpose)
    maf[0] = *(const bf16x8*)&Pl[w][l15][quad*8];
    maf[1] = *(const bf16x8*)&Pl[w][l15][32 + quad*8];
    float rs_r[4];
    #pragma unroll
    for (int rg = 0; rg < 4; rg++){
        int i = i0 + st*16 + quad*4 + rg;
        rs_r[rg] = __shfl(rsum, quad*4 + rg) + ((i < Nb) ? 1.f : 0.f);
    }

    // ---- phase B: 8 j-chunks, wave-private, barrier-free ----
    f32x4 hacc[4] = {{0,0,0,0},{0,0,0,0},{0,0,0,0},{0,0,0,0}};
    #pragma unroll
    for (int jt = 0; jt < 8; jt++){
        #pragma unroll
        for (int nt = 0; nt < 4; nt++){        // GEMM1 + tanh -> P strip (C-layout)
            float bv = bl[jt*64 + nt*16 + l15];
            f32x4 arg = { rs_r[0]*bv, rs_r[1]*bv, rs_r[2]*bv, rs_r[3]*bv };
            #pragma unroll
            for (int ks = 0; ks < 2; ks++){
                bf16x8 bfr = *(const bf16x8*)&XWhL[jt*64 + nt*16 + l15][ks*32 + quad*8];
                arg = __builtin_amdgcn_mfma_f32_16x16x32_bf16(maf[ks], bfr, arg, 0, 0, 0);
            }
            #pragma unroll
            for (int rg = 0; rg < 4; rg++)
                Pl[w][quad*4 + rg][nt*16 + l15] = f2bf(fast_tanh(arg[rg]));
        }
        asm volatile("s_waitcnt lgkmcnt(0)" ::: "memory");
        __builtin_amdgcn_sched_barrier(0);
        #pragma unroll
        for (int ks = 0; ks < 2; ks++){        // GEMM2: H strip += P strip @ XW
            bf16x8 paf = *(const bf16x8*)&Pl[w][l15][ks*32 + quad*8];
            #pragma unroll
            for (int dt = 0; dt < 4; dt++){
                bf16x8 bfr = *(const bf16x8*)&XWtL[dt*16 + l15][jt*64 + ks*32 + quad*8];
                hacc[dt] = __builtin_amdgcn_mfma_f32_16x16x32_bf16(paf, bfr, hacc[dt], 0, 0, 0);
            }
        }
    }
    #pragma unroll
    for (int dt = 0; dt < 4; dt++){
        float bw = bias_W[dt*16 + l15];
        #pragma unroll
        for (int rg = 0; rg < 4; rg++)
            H[(size_t)(b*NN + i0 + st*16 + quad*4 + rg)*FD + dt*16 + l15] = hacc[dt][rg] + bw;
    }
}

extern "C" void kernel_launch(void* const* d_in, const int* in_sizes, int n_in,
                              void* d_out, int out_size, void* d_ws, size_t ws_size,
                              hipStream_t stream){
    const float* X      = (const float*)d_in[0];
    const float* A      = (const float*)d_in[1];
    const int*   N      = (const int*)  d_in[2];
    const float* W      = (const float*)d_in[3];
    const float* a      = (const float*)d_in[4];
    const float* bias_W = (const float*)d_in[5];
    const float* bias_a = (const float*)d_in[6];
    float* H = (float*)d_out;
    char* ws = (char*)d_ws;

    unsigned short* XWh    = (unsigned short*)(ws);                    // 4 MB
    unsigned short* XWt    = (unsigned short*)(ws + (4u<<20));         // 4 MB
    float*          colsum = (float*)(ws + (8u<<20));                  // 256 B

    k_xw   <<<BB * NN / 64, 256, 0, stream>>>(X, W, a, colsum, XWh, XWt);
    k_fused<<<dim3(BB, 4), 512, 0, stream>>>(A, XWh, XWt, colsum, N, bias_a, bias_W, H);
}

// Round 4
// 126.943 us; speedup vs baseline: 1.3056x; 1.0083x over previous
//
#include <hip/hip_runtime.h>

#define BB 64
#define NN 512
#define FD 64

typedef short bf16x8 __attribute__((ext_vector_type(8)));
typedef float f32x4 __attribute__((ext_vector_type(4)));

__device__ __forceinline__ unsigned short f2bf(float f){
    unsigned u = __builtin_bit_cast(unsigned, f);
    u += 0x7fffu + ((u >> 16) & 1u);           // RNE
    return (unsigned short)(u >> 16);
}
__device__ __forceinline__ float bf2f(unsigned short h){
    unsigned u = ((unsigned)h) << 16;
    return __builtin_bit_cast(float, u);
}
__device__ __forceinline__ float fast_tanh(float x){
    float e = __expf(2.0f * x);                 // inf -> 1, 0 -> -1: saturates correctly
    return 1.0f - 2.0f * __builtin_amdgcn_rcpf(e + 1.0f);
}
__device__ __forceinline__ bf16x8 pack8(float4 a, float4 b){
    bf16x8 r;
    r[0]=(short)f2bf(a.x); r[1]=(short)f2bf(a.y); r[2]=(short)f2bf(a.z); r[3]=(short)f2bf(a.w);
    r[4]=(short)f2bf(b.x); r[5]=(short)f2bf(b.y); r[6]=(short)f2bf(b.z); r[7]=(short)f2bf(b.w);
    return r;
}

// colsum[d] = sum_i a[i][d];  Wt[d][c] = bf16(W[c][d])   (round-0 verified kernel)
__global__ __launch_bounds__(256) void k_prep(const float* __restrict__ W,
                                              const float* __restrict__ a,
                                              float* __restrict__ colsum,
                                              unsigned short* __restrict__ Wt){
    __shared__ float Wl[64][68];
    __shared__ float cpart[4][64];
    int t = threadIdx.x;
    int d = t & 63, part = t >> 6;
    float s = 0.f;
    #pragma unroll
    for (int i = 0; i < 16; i++) s += a[(part*16 + i)*64 + d];
    cpart[part][d] = s;
    int r = t >> 2, c0 = (t & 3) * 16;
    {
        const float4* src = (const float4*)&W[r*64 + c0];
        #pragma unroll
        for (int q = 0; q < 4; q++) *(float4*)&Wl[r][c0 + q*4] = src[q];
    }
    __syncthreads();
    if (part == 0) colsum[d] = cpart[0][d] + cpart[1][d] + cpart[2][d] + cpart[3][d];
    #pragma unroll
    for (int q = 0; q < 4; q++){
        ushort4 o;
        #pragma unroll
        for (int jj = 0; jj < 4; jj++)
            ((unsigned short*)&o)[jj] = f2bf(Wl[c0 + q*4 + jj][r]);
        *(ushort4*)&Wt[r*64 + c0 + q*4] = o;
    }
}

// XWhL chunk-XOR swizzle: linear [512][128B] rows; 16B chunk index ^= (row&7).
// One formula for ALL access sites (write, diag read, GEMM1 b128 read).
#define XWH_BYTE(n, f)  ((unsigned)(n)*128u + (((((unsigned)(f) >> 3) ^ ((unsigned)(n) & 7u)) & 7u) << 4) + (((unsigned)(f) & 7u) << 1))
#define XWH_B128(n, f0) ((unsigned)(n)*128u + (((((unsigned)(f0) >> 3) ^ ((unsigned)(n) & 7u)) & 7u) << 4))

// v4: single fused kernel computes XW in-block (k_xw eliminated).
// Block = (batch b, it2); 8 waves. Prologue: issue X-frag loads + A-prefetch early,
// stage Wt (8KB) -> barrier1 -> per-wave XW compute (wave w owns XW rows [64w,64w+64)),
// write both LDS layouts -> barrier2 -> wave-private phase A / B exactly as v3.
// 3 barriers total; everything else wave-private (lgkmcnt only).
__global__ __launch_bounds__(512, 1) void k_fused(const float* __restrict__ X,
                                               const float* __restrict__ A,
                                               const unsigned short* __restrict__ Wt,
                                               const float* __restrict__ colsum,
                                               const int* __restrict__ Ni,
                                               const float* __restrict__ bias_a,
                                               const float* __restrict__ bias_W,
                                               float* __restrict__ H){
    __shared__ unsigned short XWtL[64][520];       // [f][n] row 1040B (bank drift 4/row)
    __shared__ unsigned short XWhL[512*64];        // [n][f] linear 128B rows, chunk-XOR swizzled
    __shared__ unsigned short Pl[8][16][72];       // per-wave M/P strip
    __shared__ unsigned short Wtl[64][72];         // Wt bf16 [d][c]
    __shared__ float bl[512];                      // bias_a
    __shared__ float csl[64];                      // colsum
    int t = threadIdx.x;
    int b = blockIdx.x, it2 = blockIdx.y;
    int lane = t & 63, w = t >> 6, l15 = lane & 15, quad = lane >> 4;
    int tl = w >> 2, st = w & 3;
    int i0 = (it2 + 4*tl) * 64;
    int Nb = (Ni[1] == 0) ? Ni[2*b] : Ni[b];       // int64 vs int32 layout
    const float* Xb = X + (size_t)b*NN*FD;
    const float* Arow = A + (size_t)(b*NN + i0 + st*16 + l15)*NN + quad*8;

    // ---- issue global loads early: X fragments for XW compute + A prefetch ----
    float4 xv[8][2];                               // wave w computes XW rows [64w, 64w+64)
    #pragma unroll
    for (int rt = 0; rt < 4; rt++)
        #pragma unroll
        for (int ks = 0; ks < 2; ks++){
            const float* p = &Xb[(w*64 + rt*16 + l15)*FD + ks*32 + quad*8];
            xv[rt*2 + ks][0] = *(const float4*)p;
            xv[rt*2 + ks][1] = *(const float4*)(p + 4);
        }
    float4 pa[4][2];
    #pragma unroll
    for (int s = 0; s < 4; s++){
        pa[s][0] = *(const float4*)&Arow[s*32];
        pa[s][1] = *(const float4*)&Arow[s*32 + 4];
    }
    // stage Wt (64x64 bf16 = 8KB = 512 threads x 16B), bias, colsum
    *(uint4*)&Wtl[t >> 3][(t & 7)*8] = *(const uint4*)&Wt[(t >> 3)*64 + (t & 7)*8];
    bl[t] = bias_a[t];
    if (t < 64) csl[t] = colsum[t];
    __syncthreads();                               // barrier 1: Wtl ready

    // ---- in-block XW = X @ W: wave-private 64-row slab, write both layouts ----
    #pragma unroll
    for (int rt = 0; rt < 4; rt++){
        f32x4 c[4] = {{0,0,0,0},{0,0,0,0},{0,0,0,0},{0,0,0,0}};
        #pragma unroll
        for (int ks = 0; ks < 2; ks++){
            bf16x8 af = pack8(xv[rt*2 + ks][0], xv[rt*2 + ks][1]);
            #pragma unroll
            for (int nt = 0; nt < 4; nt++){
                bf16x8 bfr = *(const bf16x8*)&Wtl[nt*16 + l15][ks*32 + quad*8];
                c[nt] = __builtin_amdgcn_mfma_f32_16x16x32_bf16(af, bfr, c[nt], 0, 0, 0);
            }
        }
        #pragma unroll
        for (int nt = 0; nt < 4; nt++)
            #pragma unroll
            for (int rg = 0; rg < 4; rg++){
                unsigned short hb = f2bf(c[nt][rg]);
                int n = w*64 + rt*16 + quad*4 + rg, f = nt*16 + l15;
                *(unsigned short*)((char*)XWhL + XWH_BYTE(n, f)) = hb;
                XWtL[f][n] = hb;
            }
    }
    __syncthreads();                               // barrier 2: XW staged (both layouts)

    // ---- phase A: M strip = (A_ @ XW) rows [st*16,..), all 64 f ----
    f32x4 acc[4] = {{0,0,0,0},{0,0,0,0},{0,0,0,0},{0,0,0,0}};
    float rs = 0.f;
    #pragma unroll
    for (int s = 0; s < 16; s++){
        float4 v0 = pa[s & 3][0], v1 = pa[s & 3][1];
        if (s < 12){                               // rotate prefetch 4 k-steps ahead
            pa[s & 3][0] = *(const float4*)&Arow[(s + 4)*32];
            pa[s & 3][1] = *(const float4*)&Arow[(s + 4)*32 + 4];
        }
        rs += (v0.x + v0.y) + (v0.z + v0.w) + (v1.x + v1.y) + (v1.z + v1.w);
        bf16x8 af = pack8(v0, v1);
        #pragma unroll
        for (int nt = 0; nt < 4; nt++){
            bf16x8 bfr = *(const bf16x8*)&XWtL[nt*16 + l15][s*32 + quad*8];
            acc[nt] = __builtin_amdgcn_mfma_f32_16x16x32_bf16(af, bfr, acc[nt], 0, 0, 0);
        }
    }
    // diagonal of A_ (identity on first Nb rows): acc += XW[i][f]
    #pragma unroll
    for (int nt = 0; nt < 4; nt++)
        #pragma unroll
        for (int rg = 0; rg < 4; rg++){
            int i = i0 + st*16 + quad*4 + rg;
            if (i < Nb)
                acc[nt][rg] += bf2f(*(const unsigned short*)((const char*)XWhL + XWH_BYTE(i, nt*16 + l15)));
        }
    // in-wave rowsum: every lane ends holding rowsum(row l15)
    float rsum = rs;
    rsum += __shfl_xor(rsum, 16);
    rsum += __shfl_xor(rsum, 32);
    // M = acc * colsum[col] -> private strip (C-layout)
    #pragma unroll
    for (int nt = 0; nt < 4; nt++){
        float cs = csl[nt*16 + l15];
        #pragma unroll
        for (int rg = 0; rg < 4; rg++)
            Pl[w][quad*4 + rg][nt*16 + l15] = f2bf(acc[nt][rg] * cs);
    }
    asm volatile("s_waitcnt lgkmcnt(0)" ::: "memory");
    __builtin_amdgcn_sched_barrier(0);
    bf16x8 maf[2];                                 // A-layout M fragments (in-wave transpose)
    maf[0] = *(const bf16x8*)&Pl[w][l15][quad*8];
    maf[1] = *(const bf16x8*)&Pl[w][l15][32 + quad*8];
    float rs_r[4];
    #pragma unroll
    for (int rg = 0; rg < 4; rg++){
        int i = i0 + st*16 + quad*4 + rg;
        rs_r[rg] = __shfl(rsum, quad*4 + rg) + ((i < Nb) ? 1.f : 0.f);
    }

    // ---- phase B: 8 j-chunks, wave-private, barrier-free ----
    f32x4 hacc[4] = {{0,0,0,0},{0,0,0,0},{0,0,0,0},{0,0,0,0}};
    #pragma unroll
    for (int jt = 0; jt < 8; jt++){
        #pragma unroll
        for (int nt = 0; nt < 4; nt++){            // GEMM1 + tanh -> P strip (C-layout)
            int j = jt*64 + nt*16 + l15;
            float bv = bl[j];
            f32x4 arg = { rs_r[0]*bv, rs_r[1]*bv, rs_r[2]*bv, rs_r[3]*bv };
            #pragma unroll
            for (int ks = 0; ks < 2; ks++){
                bf16x8 bfr = *(const bf16x8*)((const char*)XWhL + XWH_B128(j, ks*32 + quad*8));
                arg = __builtin_amdgcn_mfma_f32_16x16x32_bf16(maf[ks], bfr, arg, 0, 0, 0);
            }
            #pragma unroll
            for (int rg = 0; rg < 4; rg++)
                Pl[w][quad*4 + rg][nt*16 + l15] = f2bf(fast_tanh(arg[rg]));
        }
        asm volatile("s_waitcnt lgkmcnt(0)" ::: "memory");
        __builtin_amdgcn_sched_barrier(0);
        #pragma unroll
        for (int ks = 0; ks < 2; ks++){            // GEMM2: H strip += P strip @ XW
            bf16x8 paf = *(const bf16x8*)&Pl[w][l15][ks*32 + quad*8];
            #pragma unroll
            for (int dt = 0; dt < 4; dt++){
                bf16x8 bfr = *(const bf16x8*)&XWtL[dt*16 + l15][jt*64 + ks*32 + quad*8];
                hacc[dt] = __builtin_amdgcn_mfma_f32_16x16x32_bf16(paf, bfr, hacc[dt], 0, 0, 0);
            }
        }
    }
    #pragma unroll
    for (int dt = 0; dt < 4; dt++){
        float bw = bias_W[dt*16 + l15];
        #pragma unroll
        for (int rg = 0; rg < 4; rg++)
            H[(size_t)(b*NN + i0 + st*16 + quad*4 + rg)*FD + dt*16 + l15] = hacc[dt][rg] + bw;
    }
}

extern "C" void kernel_launch(void* const* d_in, const int* in_sizes, int n_in,
                              void* d_out, int out_size, void* d_ws, size_t ws_size,
                              hipStream_t stream){
    const float* X      = (const float*)d_in[0];
    const float* A      = (const float*)d_in[1];
    const int*   N      = (const int*)  d_in[2];
    const float* W      = (const float*)d_in[3];
    const float* a      = (const float*)d_in[4];
    const float* bias_W = (const float*)d_in[5];
    const float* bias_a = (const float*)d_in[6];
    float* H = (float*)d_out;
    char* ws = (char*)d_ws;

    unsigned short* Wt     = (unsigned short*)(ws);            // 8 KB
    float*          colsum = (float*)(ws + 8192);              // 256 B

    k_prep <<<1, 256, 0, stream>>>(W, a, colsum, Wt);
    k_fused<<<dim3(BB, 4), 512, 0, stream>>>(X, A, Wt, colsum, N, bias_a, bias_W, H);
}

// Round 5
// 124.320 us; speedup vs baseline: 1.3331x; 1.0211x over previous
//
#include <hip/hip_runtime.h>

#define BB 64
#define NN 512
#define FD 64

typedef short bf16x8 __attribute__((ext_vector_type(8)));
typedef float f32x4 __attribute__((ext_vector_type(4)));

__device__ __forceinline__ unsigned short f2bf(float f){
    unsigned u = __builtin_bit_cast(unsigned, f);
    u += 0x7fffu + ((u >> 16) & 1u);           // RNE
    return (unsigned short)(u >> 16);
}
__device__ __forceinline__ float bf2f(unsigned short h){
    unsigned u = ((unsigned)h) << 16;
    return __builtin_bit_cast(float, u);
}
__device__ __forceinline__ unsigned pkbf2(float a, float b){
    return (unsigned)f2bf(a) | ((unsigned)f2bf(b) << 16);
}
__device__ __forceinline__ float fast_tanh(float x){
    float e = __expf(2.0f * x);                 // inf -> 1, 0 -> -1: saturates correctly
    return 1.0f - 2.0f * __builtin_amdgcn_rcpf(e + 1.0f);
}
__device__ __forceinline__ bf16x8 pack8(float4 a, float4 b){
    bf16x8 r;
    r[0]=(short)f2bf(a.x); r[1]=(short)f2bf(a.y); r[2]=(short)f2bf(a.z); r[3]=(short)f2bf(a.w);
    r[4]=(short)f2bf(b.x); r[5]=(short)f2bf(b.y); r[6]=(short)f2bf(b.z); r[7]=(short)f2bf(b.w);
    return r;
}

// colsum[d] = sum_i a[i][d];  Wt[d][c] = bf16(W[c][d])   (round-0 verified kernel)
__global__ __launch_bounds__(256) void k_prep(const float* __restrict__ W,
                                              const float* __restrict__ a,
                                              float* __restrict__ colsum,
                                              unsigned short* __restrict__ Wt){
    __shared__ float Wl[64][68];
    __shared__ float cpart[4][64];
    int t = threadIdx.x;
    int d = t & 63, part = t >> 6;
    float s = 0.f;
    #pragma unroll
    for (int i = 0; i < 16; i++) s += a[(part*16 + i)*64 + d];
    cpart[part][d] = s;
    int r = t >> 2, c0 = (t & 3) * 16;
    {
        const float4* src = (const float4*)&W[r*64 + c0];
        #pragma unroll
        for (int q = 0; q < 4; q++) *(float4*)&Wl[r][c0 + q*4] = src[q];
    }
    __syncthreads();
    if (part == 0) colsum[d] = cpart[0][d] + cpart[1][d] + cpart[2][d] + cpart[3][d];
    #pragma unroll
    for (int q = 0; q < 4; q++){
        ushort4 o;
        #pragma unroll
        for (int jj = 0; jj < 4; jj++)
            ((unsigned short*)&o)[jj] = f2bf(Wl[c0 + q*4 + jj][r]);
        *(ushort4*)&Wt[r*64 + c0 + q*4] = o;
    }
}

// v5: all-swapped-orientation fused kernel, ONE barrier, zero scalar LDS scatter.
// The MFMA C-layout (row=quad*4+rg in-lane, col=l15) means: whichever operand is A
// determines which dim is rg-adjacent in-lane -> choose orientation per product so
// every LDS write is a packed b64 and every LDS read is a row-aligned b128/b64:
//   XW:     mfma(X,Wt) -> n-packed b64 into XWtL;  mfma(Wt,X) -> f-packed b64 into XWhL
//   phaseA: mfma(XWt,Arow) -> M f-in-lane -> b64 strip writes; diag-add = b64 reads
//   GEMM1:  mfma(XWh,M)  -> P j-in-lane  -> b64 strip writes in GEMM2's B layout
//   GEMM2:  mfma(XWt,P)  -> H f-in-lane  -> float4 global stores
// A-prefetch depth 8 (16 loads in flight); Wt fragments read from global (L2-hot),
// so the Wtl stage and its barrier disappear.
__global__ __launch_bounds__(512, 1) void k_fused(const float* __restrict__ X,
                                               const float* __restrict__ A,
                                               const unsigned short* __restrict__ Wt,
                                               const float* __restrict__ colsum,
                                               const int* __restrict__ Ni,
                                               const float* __restrict__ bias_a,
                                               const float* __restrict__ bias_W,
                                               float* __restrict__ H){
    __shared__ unsigned short XWtL[64][520];   // [f][n], row 1040B (16B-mult)
    __shared__ unsigned short XWhL[512][72];   // [n][f], row 144B  (16B-mult)
    __shared__ unsigned short Pl[8][16][72];   // per-wave M/P strip [i][f or j]
    __shared__ float bl[512];                  // bias_a
    __shared__ float csl[64];                  // colsum
    int t = threadIdx.x;
    int b = blockIdx.x, it2 = blockIdx.y;
    int lane = t & 63, w = t >> 6, l15 = lane & 15, quad = lane >> 4;
    int tl = w >> 2, st = w & 3;
    int i0 = (it2 + 4*tl) * 64;
    int Nb = (Ni[1] == 0) ? Ni[2*b] : Ni[b];   // int64 vs int32 layout
    const float* Xb = X + (size_t)b*NN*FD;
    const float* Arow = A + (size_t)(b*NN + i0 + st*16 + l15)*NN + quad*8;

    // ---- prologue: issue X fragments + Wt fragments (global, L2-hot); stage bias ----
    float4 xv[8][2];                           // wave w computes XW rows [64w, 64w+64)
    #pragma unroll
    for (int rt = 0; rt < 4; rt++)
        #pragma unroll
        for (int ks = 0; ks < 2; ks++){
            const float* p = &Xb[(w*64 + rt*16 + l15)*FD + ks*32 + quad*8];
            xv[rt*2 + ks][0] = *(const float4*)p;
            xv[rt*2 + ks][1] = *(const float4*)(p + 4);
        }
    bf16x8 wf[4][2];                           // Wt[f][c] row fragments
    #pragma unroll
    for (int ft = 0; ft < 4; ft++)
        #pragma unroll
        for (int ks = 0; ks < 2; ks++)
            wf[ft][ks] = *(const bf16x8*)&Wt[(ft*16 + l15)*64 + ks*32 + quad*8];
    bl[t] = bias_a[t];
    if (t < 64) csl[t] = colsum[t];

    // ---- XW both orientations, packed b64 writes only ----
    #pragma unroll
    for (int rt = 0; rt < 4; rt++){
        bf16x8 af0 = pack8(xv[rt*2][0],     xv[rt*2][1]);       // ks=0
        bf16x8 af1 = pack8(xv[rt*2 + 1][0], xv[rt*2 + 1][1]);   // ks=1
        f32x4 c[4]  = {{0,0,0,0},{0,0,0,0},{0,0,0,0},{0,0,0,0}};
        f32x4 ct[4] = {{0,0,0,0},{0,0,0,0},{0,0,0,0},{0,0,0,0}};
        #pragma unroll
        for (int nt = 0; nt < 4; nt++){
            c[nt]  = __builtin_amdgcn_mfma_f32_16x16x32_bf16(af0, wf[nt][0], c[nt], 0, 0, 0);
            c[nt]  = __builtin_amdgcn_mfma_f32_16x16x32_bf16(af1, wf[nt][1], c[nt], 0, 0, 0);
            ct[nt] = __builtin_amdgcn_mfma_f32_16x16x32_bf16(wf[nt][0], af0, ct[nt], 0, 0, 0);
            ct[nt] = __builtin_amdgcn_mfma_f32_16x16x32_bf16(wf[nt][1], af1, ct[nt], 0, 0, 0);
        }
        int n0 = w*64 + rt*16;
        #pragma unroll
        for (int nt = 0; nt < 4; nt++){        // XWtL[f][n]: n (=rg) in-lane -> b64
            uint2 pk = { pkbf2(c[nt][0], c[nt][1]), pkbf2(c[nt][2], c[nt][3]) };
            *(uint2*)&XWtL[nt*16 + l15][n0 + quad*4] = pk;
        }
        #pragma unroll
        for (int ft = 0; ft < 4; ft++){        // XWhL[n][f]: f (=rg) in-lane -> b64
            uint2 pk = { pkbf2(ct[ft][0], ct[ft][1]), pkbf2(ct[ft][2], ct[ft][3]) };
            *(uint2*)&XWhL[n0 + l15][ft*16 + quad*4] = pk;
        }
    }
    // A prefetch depth 8 (latency overlaps XW write drain + barrier)
    float4 pa[8][2];
    #pragma unroll
    for (int s = 0; s < 8; s++){
        pa[s][0] = *(const float4*)&Arow[s*32];
        pa[s][1] = *(const float4*)&Arow[s*32 + 4];
    }
    __syncthreads();                           // the kernel's ONLY barrier

    // ---- phase A (swapped): Mt[f][i], i = l15, f = nt*16 + quad*4 + rg ----
    f32x4 acc[4] = {{0,0,0,0},{0,0,0,0},{0,0,0,0},{0,0,0,0}};
    float rs = 0.f;
    #pragma unroll
    for (int s = 0; s < 16; s++){
        float4 v0 = pa[s & 7][0], v1 = pa[s & 7][1];
        if (s < 8){                            // rotate prefetch 8 k-steps ahead
            pa[s & 7][0] = *(const float4*)&Arow[(s + 8)*32];
            pa[s & 7][1] = *(const float4*)&Arow[(s + 8)*32 + 4];
        }
        rs += (v0.x + v0.y) + (v0.z + v0.w) + (v1.x + v1.y) + (v1.z + v1.w);
        bf16x8 af = pack8(v0, v1);
        #pragma unroll
        for (int nt = 0; nt < 4; nt++){
            bf16x8 xa = *(const bf16x8*)&XWtL[nt*16 + l15][s*32 + quad*8];
            acc[nt] = __builtin_amdgcn_mfma_f32_16x16x32_bf16(xa, af, acc[nt], 0, 0, 0);
        }
    }
    int irow = i0 + st*16 + l15;               // this lane's i (output column)
    bool dg = irow < Nb;
    // diag add (b64 reads), colsum scale, M strip write (b64, row layout [i][f])
    #pragma unroll
    for (int nt = 0; nt < 4; nt++){
        float4 cs4 = *(const float4*)&csl[nt*16 + quad*4];
        ushort4 dh = *(const ushort4*)&XWhL[irow][nt*16 + quad*4];
        float m0 = (acc[nt][0] + (dg ? bf2f(dh.x) : 0.f)) * cs4.x;
        float m1 = (acc[nt][1] + (dg ? bf2f(dh.y) : 0.f)) * cs4.y;
        float m2 = (acc[nt][2] + (dg ? bf2f(dh.z) : 0.f)) * cs4.z;
        float m3 = (acc[nt][3] + (dg ? bf2f(dh.w) : 0.f)) * cs4.w;
        uint2 pk = { pkbf2(m0, m1), pkbf2(m2, m3) };
        *(uint2*)&Pl[w][l15][nt*16 + quad*4] = pk;
    }
    // in-wave rowsum: every lane ends holding rowsum(row i = l15)
    float rsum = rs;
    rsum += __shfl_xor(rsum, 16);
    rsum += __shfl_xor(rsum, 32);
    float rsum_l = rsum + (dg ? 1.f : 0.f);
    asm volatile("s_waitcnt lgkmcnt(0)" ::: "memory");
    __builtin_amdgcn_sched_barrier(0);
    bf16x8 maf[2];                             // M[i=l15][f-slice] -> GEMM1 B-operand
    maf[0] = *(const bf16x8*)&Pl[w][l15][quad*8];
    maf[1] = *(const bf16x8*)&Pl[w][l15][32 + quad*8];

    // ---- phase B: 8 j-chunks, wave-private, all-swapped ----
    f32x4 hacc[4] = {{0,0,0,0},{0,0,0,0},{0,0,0,0},{0,0,0,0}};
    float4 bwv[4];
    #pragma unroll
    for (int dt = 0; dt < 4; dt++) bwv[dt] = *(const float4*)&bias_W[dt*16 + quad*4];
    #pragma unroll
    for (int jt = 0; jt < 8; jt++){
        #pragma unroll
        for (int nt = 0; nt < 4; nt++){        // GEMM1 swapped: att^T (j rows, i=l15 cols)
            float4 blv = *(const float4*)&bl[jt*64 + nt*16 + quad*4];
            f32x4 arg = { rsum_l*blv.x, rsum_l*blv.y, rsum_l*blv.z, rsum_l*blv.w };
            #pragma unroll
            for (int ks = 0; ks < 2; ks++){
                bf16x8 xh = *(const bf16x8*)&XWhL[jt*64 + nt*16 + l15][ks*32 + quad*8];
                arg = __builtin_amdgcn_mfma_f32_16x16x32_bf16(xh, maf[ks], arg, 0, 0, 0);
            }
            uint2 pk = { pkbf2(fast_tanh(arg[0]), fast_tanh(arg[1])),
                         pkbf2(fast_tanh(arg[2]), fast_tanh(arg[3])) };
            *(uint2*)&Pl[w][l15][nt*16 + quad*4] = pk;   // P[i=l15][j-local], GEMM2-ready
        }
        asm volatile("s_waitcnt lgkmcnt(0)" ::: "memory");
        __builtin_amdgcn_sched_barrier(0);
        #pragma unroll
        for (int ks = 0; ks < 2; ks++){        // GEMM2 swapped: H^T (d rows, i=l15 cols)
            bf16x8 pf = *(const bf16x8*)&Pl[w][l15][ks*32 + quad*8];
            #pragma unroll
            for (int dt = 0; dt < 4; dt++){
                bf16x8 xt = *(const bf16x8*)&XWtL[dt*16 + l15][jt*64 + ks*32 + quad*8];
                hacc[dt] = __builtin_amdgcn_mfma_f32_16x16x32_bf16(xt, pf, hacc[dt], 0, 0, 0);
            }
        }
    }
    // ---- store: f in-lane -> float4 stores ----
    float* Hrow = H + (size_t)(b*NN + irow)*FD;
    #pragma unroll
    for (int dt = 0; dt < 4; dt++){
        float4 hv = { hacc[dt][0] + bwv[dt].x, hacc[dt][1] + bwv[dt].y,
                      hacc[dt][2] + bwv[dt].z, hacc[dt][3] + bwv[dt].w };
        *(float4*)&Hrow[dt*16 + quad*4] = hv;
    }
}

extern "C" void kernel_launch(void* const* d_in, const int* in_sizes, int n_in,
                              void* d_out, int out_size, void* d_ws, size_t ws_size,
                              hipStream_t stream){
    const float* X      = (const float*)d_in[0];
    const float* A      = (const float*)d_in[1];
    const int*   N      = (const int*)  d_in[2];
    const float* W      = (const float*)d_in[3];
    const float* a      = (const float*)d_in[4];
    const float* bias_W = (const float*)d_in[5];
    const float* bias_a = (const float*)d_in[6];
    float* H = (float*)d_out;
    char* ws = (char*)d_ws;

    unsigned short* Wt     = (unsigned short*)(ws);            // 8 KB
    float*          colsum = (float*)(ws + 8192);              // 256 B

    k_prep <<<1, 256, 0, stream>>>(W, a, colsum, Wt);
    k_fused<<<dim3(BB, 4), 512, 0, stream>>>(X, A, Wt, colsum, N, bias_a, bias_W, H);
}